// Round 7
// baseline (567.020 us; speedup 1.0000x reference)
//
#include <hip/hip_runtime.h>

// ---------------------------------------------------------------------------
// BertAttention (relative_key_query) on MI355X. FP32 I/O, bf16 MFMA compute.
// B=8 S=1024 E=1024 H=16 D=64 M=1024
// R14: attn = R11 G-layout (stride-64 XOR8, measured-best 2.94e7 conflicts;
// R12 stride-66 and R13 stride-70 both measured worse) + R12 XCD remap +
// sK stride 76 (probs-store bank fix: 24q mod 32 distinct per quad) +
// GEMM grid transpose (x = n-row-block -> A-panel pinned per XCD via idx%8
// round-robin => A L2-resident, QKV A-traffic ~128MB -> ~16MB).
// ---------------------------------------------------------------------------

typedef unsigned short u16;
typedef unsigned int u32;
typedef unsigned long long u64;
typedef __bf16 bf16x8 __attribute__((ext_vector_type(8)));
typedef float  f32x4  __attribute__((ext_vector_type(4)));
typedef int    i32x4  __attribute__((ext_vector_type(4)));

__device__ __forceinline__ float b2f(u16 u) {
  union { u32 i; float f; } x;
  x.i = ((u32)u) << 16;
  return x.f;
}
__device__ __forceinline__ u16 f2b_manual(float f) {
  union { float f; u32 u; } x;
  x.f = f;
  return (u16)((x.u + 0x7FFFu + ((x.u >> 16) & 1u)) >> 16);
}
#if __has_builtin(__builtin_amdgcn_cvt_pk_bf16_f32)
typedef __bf16 bf16x2 __attribute__((ext_vector_type(2)));
__device__ __forceinline__ u32 cvt2(float a, float b) {
  union { bf16x2 v; u32 u; } x;
  x.v = __builtin_amdgcn_cvt_pk_bf16_f32(a, b);
  return x.u;
}
#else
__device__ __forceinline__ u32 cvt2(float a, float b) {
  return (u32)f2b_manual(a) | ((u32)f2b_manual(b) << 16);
}
#endif
__device__ __forceinline__ u16 f2b(float f) { return (u16)(cvt2(f, f) & 0xffffu); }

union LdU { i32x4 i4; bf16x8 b8; };
__device__ __forceinline__ bf16x8 ldb8(const u16* p) {
  LdU u; u.i4 = *(const i32x4*)p; return u.b8;
}
__device__ __forceinline__ void pack8(u16* dst, const float* src) {
  f32x4 lo = *(const f32x4*)src, hi = *(const f32x4*)(src + 4);
  i32x4 v;
  v.x = (int)cvt2(lo.x, lo.y); v.y = (int)cvt2(lo.z, lo.w);
  v.z = (int)cvt2(hi.x, hi.y); v.w = (int)cvt2(hi.z, hi.w);
  *(i32x4*)dst = v;
}
#define MFMA16(a, b, c) __builtin_amdgcn_mfma_f32_16x16x32_bf16((a), (b), (c), 0, 0, 0)

template <int C>
__device__ __forceinline__ float dppmov(float x) {
  union { float f; int i; } a, r;
  a.f = x;
  r.i = __builtin_amdgcn_update_dpp(0, a.i, C, 0xF, 0xF, true);
  return r.f;
}
__device__ __forceinline__ float rsum16(float x) {
  x += dppmov<0xB1>(x);   // quad_perm xor1
  x += dppmov<0x4E>(x);   // quad_perm xor2
  x += dppmov<0x141>(x);  // row_half_mirror (^7)
  x += dppmov<0x140>(x);  // row_mirror (^15)
  return x;
}
__device__ __forceinline__ float fexp2(float x) {
#if __has_builtin(__builtin_amdgcn_exp2f)
  return __builtin_amdgcn_exp2f(x);
#else
  return exp2f(x);
#endif
}

// async global->LDS 16B/lane; LDS dest must be wave-uniform base (HW adds
// lane*16). Fallback: manual copy producing identical layout.
#if __has_builtin(__builtin_amdgcn_global_load_lds)
#define HAS_GLDS 1
typedef __attribute__((address_space(3))) u32 as3_u32;
typedef const __attribute__((address_space(1))) u32 as1_u32;
__device__ __forceinline__ void gld16(const u16* g, u16* lds_wave_base) {
  __builtin_amdgcn_global_load_lds(
      (as1_u32*)g, (as3_u32*)(u32)(u64)lds_wave_base, 16, 0, 0);
}
#else
#define HAS_GLDS 0
__device__ __forceinline__ void gld16_fb(const u16* g, u16* lds_wave_base,
                                         int lane) {
  *(i32x4*)(lds_wave_base + lane * 8) = *(const i32x4*)g;
}
#endif

// sqrt(0.125 * log2(e)) — folded into Q, K, dist at conversion time so the
// softmax exponent needs no per-element scale.
#define SQRT_C2 0.42466090f

// ---------------------------------------------------------------------------
__global__ __launch_bounds__(256) void convX(
    const float* __restrict__ X, u16* __restrict__ Xb) {
  int i = (blockIdx.x * 256 + threadIdx.x) * 8;
  pack8(&Xb[i], &X[i]);
}

__global__ __launch_bounds__(256) void convD(
    const float* __restrict__ dist, u16* __restrict__ distb) {
  int i = (blockIdx.x * 256 + threadIdx.x) * 8;
  if (i < 2047 * 64) {
    float t[8];
#pragma unroll
    for (int j = 0; j < 8; j++) t[j] = dist[i + j] * SQRT_C2;
    pack8(&distb[i], t);
  }
}

// convWt: W[1024][1024] fp32 -> Wt[m][k] bf16 (transposed), 64x64 LDS tiles.
__global__ __launch_bounds__(256) void convWt(
    const float* __restrict__ W, u16* __restrict__ Wt) {
  __shared__ float tile[64][65];
  const int tid = threadIdx.x;
  const int k0 = blockIdx.x * 64, m0 = blockIdx.y * 64;
#pragma unroll
  for (int it = 0; it < 4; it++) {
    int row = (tid >> 4) + 16 * it;
    int col = (tid & 15) * 4;
    f32x4 v = *(const f32x4*)&W[(size_t)(k0 + row) * 1024 + m0 + col];
    tile[row][col] = v.x; tile[row][col + 1] = v.y;
    tile[row][col + 2] = v.z; tile[row][col + 3] = v.w;
  }
  __syncthreads();
#pragma unroll
  for (int it = 0; it < 4; it++) {
    int mr = (tid >> 4) + 16 * it;
    int kc = (tid & 15) * 4;
    u32 w0 = cvt2(tile[kc][mr], tile[kc + 1][mr]);
    u32 w1 = cvt2(tile[kc + 2][mr], tile[kc + 3][mr]);
    *(u64*)&Wt[(size_t)(m0 + mr) * 1024 + k0 + kc] = (u64)w0 | ((u64)w1 << 32);
  }
}

// transV: Vw[b*1024+s][h*64+d] bf16 -> Vt[bh][d][s] bf16.
__global__ __launch_bounds__(256) void transV(
    const u16* __restrict__ V, u16* __restrict__ Vt) {
  __shared__ u16 tile[64][72];
  const int tid = threadIdx.x;
  const int bh = blockIdx.y, b = bh >> 4, h = bh & 15;
  const int s0 = blockIdx.x << 6;
  const u16* Vb = V + (size_t)(b * 1024) * 1024 + h * 64;
  {
    int rp = tid >> 3, a = tid & 7;
    const u16* src = &Vb[(size_t)(s0 + 2 * rp) * 1024 + a * 8];
    i32x4 va = *(const i32x4*)src;
    i32x4 vb2 = *(const i32x4*)(src + 1024);
    u16 ta[8] __attribute__((aligned(16)));
    u16 tb[8] __attribute__((aligned(16)));
    *(i32x4*)ta = va; *(i32x4*)tb = vb2;
    int colb = ((((rp >> 2) ^ a) << 3) | ((2 * rp) & 7));
#pragma unroll
    for (int j = 0; j < 8; j++)
      *(u32*)&tile[a * 8 + j][colb] = (u32)ta[j] | ((u32)tb[j] << 16);
  }
  __syncthreads();
  int d = tid >> 2, cc = tid & 3;
  int sw = (d >> 3) & 7;
  i32x4 lo = *(const i32x4*)&tile[d][((2 * cc) ^ sw) << 3];
  i32x4 hi = *(const i32x4*)&tile[d][((2 * cc + 1) ^ sw) << 3];
  u16* dst = Vt + ((size_t)bh * 64 + d) * 1024 + s0 + cc * 16;
  *(i32x4*)dst = lo;
  *(i32x4*)(dst + 8) = hi;
}

// ---------------------------------------------------------------------------
// GEMM: out[N,M] = A[N,K] @ Wt^T + bias (+ residual). 128x128 tile, BK=64,
// 4 waves x 32x128. Staging via global_load_lds (16B/lane), XOR8 swizzle on
// the GLOBAL address. R14: grid transposed — blockIdx.x = n-row-block,
// blockIdx.y = m-col-block, so x-fastest dispatch + idx%8 XCD round-robin
// pins each A-panel to one XCD (L2-resident).
// QKV=1: M=3072 stacked; outputs split into 3 [8192][1024] segments.
// ---------------------------------------------------------------------------
template <int RESID, int OUTF32, int QKV>
__global__ __launch_bounds__(256) void gemm_bb(
    const u16* __restrict__ A, const u16* __restrict__ Wt,
    const float* __restrict__ bias, const float* __restrict__ resid,
    float* __restrict__ outF, u16* __restrict__ outB, int N, int K, int M,
    float oscale) {
  __shared__ u16 sA[128 * 64];
  __shared__ u16 sW[128 * 64];

  const int tid = threadIdx.x;
  const int lane = tid & 63, w = tid >> 6;
  const int quad = lane >> 4, lb = lane & 15;
  const int m0 = blockIdx.y * 128, n0 = blockIdx.x * 128;

  const int srow = lane >> 3;
  const int gcol = ((lane & 7) ^ srow) << 3;  // XOR8 swizzle on global side

  f32x4 acc[2][8] = {};

  for (int k0 = 0; k0 < K; k0 += 64) {
#pragma unroll
    for (int j = 0; j < 4; j++) {
      int rb = (4 * w + j) * 8;
      const u16* ga = &A[(size_t)(n0 + rb + srow) * K + k0 + gcol];
      const u16* gw = &Wt[(size_t)(m0 + rb + srow) * K + k0 + gcol];
#if HAS_GLDS
      gld16(ga, &sA[rb * 64]);
      gld16(gw, &sW[rb * 64]);
#else
      gld16_fb(ga, &sA[rb * 64], lane);
      gld16_fb(gw, &sW[rb * 64], lane);
#endif
    }
    __syncthreads();

    const int r0 = 32 * w + lb;
    const int sw0 = r0 & 7;  // (r0+16)&7 == sw0
    bf16x8 a00 = ldb8(&sA[r0 * 64 + ((quad ^ sw0) << 3)]);
    bf16x8 a01 = ldb8(&sA[r0 * 64 + (((4 + quad) ^ sw0) << 3)]);
    bf16x8 a10 = ldb8(&sA[(r0 + 16) * 64 + ((quad ^ sw0) << 3)]);
    bf16x8 a11 = ldb8(&sA[(r0 + 16) * 64 + (((4 + quad) ^ sw0) << 3)]);
#pragma unroll
    for (int t = 0; t < 8; t++) {
      int n = 16 * t + lb;
      int swn = n & 7;
      bf16x8 b0 = ldb8(&sW[n * 64 + ((quad ^ swn) << 3)]);
      bf16x8 b1 = ldb8(&sW[n * 64 + (((4 + quad) ^ swn) << 3)]);
      acc[0][t] = MFMA16(a00, b0, acc[0][t]);
      acc[0][t] = MFMA16(a01, b1, acc[0][t]);
      acc[1][t] = MFMA16(a10, b0, acc[1][t]);
      acc[1][t] = MFMA16(a11, b1, acc[1][t]);
    }
    __syncthreads();
  }

  u16* outSeg = outB;
  float osc = oscale;
  int mbase = m0;
  if (QKV) {
    outSeg = outB + (size_t)(m0 >> 10) * ((size_t)8192 * 1024);
    osc = (m0 < 2048) ? SQRT_C2 : 1.0f;
    mbase = m0 & 1023;
  }

#pragma unroll
  for (int half = 0; half < 2; half++)
#pragma unroll
    for (int t = 0; t < 8; t++) {
      int col = m0 + 16 * t + lb;       // bias index (stacked when QKV)
      int colw = mbase + 16 * t + lb;   // output col within segment
      float bv = bias[col];
#pragma unroll
      for (int i = 0; i < 4; i++) {
        int rowg = n0 + 32 * w + 16 * half + quad * 4 + i;
        float v = acc[half][t][i] + bv;
        if (RESID) v += resid[(size_t)rowg * M + col];
        v *= osc;
        if (OUTF32) outF[(size_t)rowg * M + col] = v;
        else        outSeg[(size_t)rowg * (QKV ? 1024 : M) + colw] = f2b(v);
      }
    }
}

// ---------------------------------------------------------------------------
// Fused attention: one block = (b, h, 64 q-rows), 16 k-tiles of 64.
// R11 schedule + G layout (register prefetch before QK^T, ds_write in the
// C->A gap, setprio, hoisted addrs, u-restricted G, deferred rsum,
// prescaled exp2, stride-64 XOR8 G arrays) + R12 XCD remap + R14 sK
// stride 76 (probs-store bank term 24q mod 32 = {0,24,16,8} distinct).
// ---------------------------------------------------------------------------
__global__ __launch_bounds__(256) void attn(
    const u16* __restrict__ Q, const u16* __restrict__ Kv,
    const u16* __restrict__ Vt, const u16* __restrict__ distb,
    u16* __restrict__ ctx) {
  __shared__ u16 sQ[64][72];
  __shared__ u16 sK[64][76];      // probs overlay after barrier B (stride 76)
  __shared__ u16 sVt[64][72];     // V^T [d][r]
  __shared__ u16 sP[128][72];     // dist window, circular
  __shared__ u16 sGq[128 * 64];   // Gq[c][rl], XOR8-swizzled cols
  __shared__ u16 sGk[128 * 64];   // Gk[c][cl], XOR8-swizzled cols

  const int tid = threadIdx.x;
  const int lane = tid & 63, w = tid >> 6;
  const int quad = lane >> 4, lb = lane & 15;
  // XCD-aware remap (bijective on 16x128 grid)
  const int f = blockIdx.y * 16 + blockIdx.x;
  const int xcd = f & 7, slot = f >> 3;
  const int bh = (xcd << 4) | (slot & 15);
  const int q0 = (slot >> 4) << 6;
  const int b = bh >> 4, h = bh & 15;
  const int S = 1024, E = 1024;
  const u16* Qb = Q  + (size_t)(b * S) * E + h * 64;
  const u16* Kb = Kv + (size_t)(b * S) * E + h * 64;
  const u16* Vtb = Vt + (size_t)bh * 64 * 1024;

  const int sr = tid >> 3, sc8 = (tid & 7) << 3;

  // pre-loop staging: Q, K/V tile 0, full 128-row dist window
  {
    *(i32x4*)&sQ[sr][sc8] = *(const i32x4*)&Qb[(size_t)(q0 + sr) * E + sc8];
    *(i32x4*)&sQ[sr + 32][sc8] =
        *(const i32x4*)&Qb[(size_t)(q0 + sr + 32) * E + sc8];
    *(i32x4*)&sK[sr][sc8] = *(const i32x4*)&Kb[(size_t)sr * E + sc8];
    *(i32x4*)&sK[sr + 32][sc8] =
        *(const i32x4*)&Kb[(size_t)(sr + 32) * E + sc8];
    *(i32x4*)&sVt[sr][sc8] = *(const i32x4*)&Vtb[(size_t)sr * 1024 + sc8];
    *(i32x4*)&sVt[sr + 32][sc8] =
        *(const i32x4*)&Vtb[(size_t)(sr + 32) * 1024 + sc8];
    const int dbase = q0 + 960;
#pragma unroll
    for (int j = 0; j < 4; j++) {
      int p = sr + 32 * j;
      int g = dbase + p;
      if (g > 2046) g = 2046;
      *(i32x4*)&sP[p][sc8] = *(const i32x4*)&distb[(size_t)g * 64 + sc8];
    }
  }
  __syncthreads();  // barrier A (tile 0)

  const int row = 16 * w + lb;
  bf16x8 aq0 = ldb8(&sQ[row][quad * 8]);
  bf16x8 aq1 = ldb8(&sQ[row][32 + quad * 8]);

  // ---- hoisted kt-invariant addresses (u16-element units) ----
  const u16* kb  = &sK[lb][quad * 8];        // QK B: +1216*t, +32
  const u16* vbp = &sVt[lb][quad * 8];       // PV B: +1152*t, +32
  const u16* akb = &sK[row][quad * 8];       // K/P A-frags: +0, +32
  const u16* pb  = &sP[lb][quad * 8];        // dist B: row 16u+lb -> +1152*u
  u16* gqsb = &sGq[lb * 64 + ((16 * w + 4 * quad) ^ ((lb & 7) << 3))];
  u16* gksb = &sGk[lb * 64 + ((16 * w + 4 * quad) ^ ((lb & 7) << 3))];
  u16* psb  = &sK[16 * w + 4 * quad][lb];    // probs store: +76*i+16*t
  const int rl_ = 16 * w + 4 * quad;
  const u16* gqa_[4];
  const u16* gka_[4][4];
#pragma unroll
  for (int i = 0; i < 4; i++) {
    int rl = rl_ + i;
    int c3 = rl - lb + 15;                   // c at t=3 (in [0,78])
    int sw8 = (c3 & 7) << 3;                 // t-invariant (16 | 8)
    gqa_[i] = &sGq[(c3 << 6) + (rl ^ sw8)];  // gather: +1024*(3-t)
#pragma unroll
    for (int t = 0; t < 4; t++) {
      int c = rl - (16 * t + lb) + 63;
      gka_[i][t] = &sGk[(c << 6) + ((16 * t + lb) ^ sw8)];
    }
  }
  // staging running pointers (advance per tile)
  const u16* kg0 = Kb + (size_t)(64 + sr) * E + sc8;
  const u16* kg1 = kg0 + (size_t)32 * E;
  const u16* vg0 = Vtb + (size_t)sr * 1024 + 64 + sc8;
  const u16* vg1 = vg0 + (size_t)32 * 1024;
  const u16* dg0 = distb + (size_t)(q0 - 64 + 960 + sr) * 64 + sc8;
  const u16* dg1 = dg0 + (size_t)32 * 64;
  u16* wk0 = &sK[sr][sc8];  u16* wk1 = &sK[sr + 32][sc8];
  u16* wv0 = &sVt[sr][sc8]; u16* wv1 = &sVt[sr + 32][sc8];
  u16* wp0 = &sP[sr][sc8];  u16* wp1 = &sP[sr + 32][sc8];

  const int uqlo = w, uqhi = w + 4;      // Gq active u-range (5 blocks)
  const int uklo = 3 - w, ukhi = 7 - w;  // Gk active u-range (5 blocks)

  f32x4 accO[4] = {};
  float l_i[4] = {0.f, 0.f, 0.f, 0.f};

  for (int kt = 0; kt < 16; kt++) {
    const int xorv = (kt & 1) << 6;

    // --- register prefetch of tile kt+1 ---
    i32x4 kr0, kr1, vr0, vr1, dr0, dr1;
    if (kt < 15) {
      kr0 = *(const i32x4*)kg0;
      kr1 = *(const i32x4*)kg1;
      vr0 = *(const i32x4*)vg0;
      vr1 = *(const i32x4*)vg1;
      dr0 = *(const i32x4*)dg0;
      dr1 = *(const i32x4*)dg1;
    }

    // --- QK^T ---
    __builtin_amdgcn_s_setprio(1);
    f32x4 accS[4] = {};
#pragma unroll
    for (int t = 0; t < 4; t++) {
      bf16x8 b0 = ldb8(kb + 1216 * t);
      bf16x8 b1 = ldb8(kb + 1216 * t + 32);
      accS[t] = MFMA16(aq0, b0, accS[t]);
      accS[t] = MFMA16(aq1, b1, accS[t]);
    }
    // --- rel-bias GEMMs (u-restricted; imm-folded store offsets) ---
    bf16x8 ak0 = ldb8(akb);
    bf16x8 ak1 = ldb8(akb + 32);
    const u16* pbA = pb + (xorv ? 4608 : 0);    // u<4 rows
    const u16* pbB = pb + (xorv ? -4608 : 0);   // u>=4 rows
#pragma unroll
    for (int u = 0; u < 8; u++) {
      const bool doq = (u >= uqlo) && (u <= uqhi);
      const bool dok = (u >= uklo) && (u <= ukhi);
      if (doq || dok) {
        const u16* pp = (u < 4 ? pbA : pbB) + 1152 * u;
        bf16x8 p0 = ldb8(pp);
        bf16x8 p1 = ldb8(pp + 32);
        if (doq) {
          f32x4 gq = {};
          gq = MFMA16(aq0, p0, gq);
          gq = MFMA16(aq1, p1, gq);
          *(u32*)(gqsb + 1024 * u) = cvt2(gq[0], gq[1]);
          *(u32*)(gqsb + 1024 * u + 2) = cvt2(gq[2], gq[3]);
        }
        if (dok) {
          f32x4 gk = {};
          gk = MFMA16(ak0, p0, gk);
          gk = MFMA16(ak1, p1, gk);
          *(u32*)(gksb + 1024 * u) = cvt2(gk[0], gk[1]);
          *(u32*)(gksb + 1024 * u + 2) = cvt2(gk[2], gk[3]);
        }
      }
    }
    __builtin_amdgcn_s_setprio(0);
    __syncthreads();  // barrier B (G read cross-wave; sK dead after this)

    // --- bias gather + fixed-max softmax (exp2 domain, prescaled) ---
    float pr[4][4];
#pragma unroll
    for (int t = 0; t < 4; t++) {
#pragma unroll
      for (int i = 0; i < 4; i++) {
        float s = accS[t][i] + b2f(gqa_[i][1024 * (3 - t)]) +
                  b2f(*gka_[i][t]);
        float e = fexp2(s);
        pr[t][i] = e;
        l_i[i] += e;
      }
    }

    // probs -> sK overlay (own-wave rows only; imm-folded offsets)
#pragma unroll
    for (int t = 0; t < 4; t++)
#pragma unroll
      for (int i = 0; i < 4; i++)
        psb[76 * i + 16 * t] = f2b(pr[t][i]);

    // --- PV ---
    bf16x8 ap0 = ldb8(akb);
    bf16x8 ap1 = ldb8(akb + 32);
    __builtin_amdgcn_s_setprio(1);
#pragma unroll
    for (int t = 0; t < 4; t++) {
      bf16x8 v0 = ldb8(vbp + 1152 * t);
      bf16x8 v1 = ldb8(vbp + 1152 * t + 32);
      accO[t] = MFMA16(ap0, v0, accO[t]);
      accO[t] = MFMA16(ap1, v1, accO[t]);
    }
    __builtin_amdgcn_s_setprio(0);
    __syncthreads();  // barrier C (PV reads of sK/sVt done block-wide)

    // --- write prefetched tile kt+1 to LDS; barrier A for next tile ---
    if (kt < 15) {
      const int pxn = ((kt + 1) & 1) ? 4608 : 0;
      *(i32x4*)wk0 = kr0;
      *(i32x4*)wk1 = kr1;
      *(i32x4*)wv0 = vr0;
      *(i32x4*)wv1 = vr1;
      *(i32x4*)(wp0 + pxn) = dr0;
      *(i32x4*)(wp1 + pxn) = dr1;
      kg0 += (size_t)64 * E; kg1 += (size_t)64 * E;
      vg0 += 64;             vg1 += 64;
      dg0 -= 64 * 64;        dg1 -= 64 * 64;
      __syncthreads();  // barrier A (tile kt+1)
    }
  }

#pragma unroll
  for (int i = 0; i < 4; i++) l_i[i] = rsum16(l_i[i]);

  u16* Cb = ctx + (size_t)(b * S) * E + h * 64;
#pragma unroll
  for (int t = 0; t < 4; t++)
#pragma unroll
    for (int i = 0; i < 4; i++) {
      int rl = 16 * w + quad * 4 + i;
      Cb[(size_t)(q0 + rl) * E + 16 * t + lb] = f2b(accO[t][i] / l_i[i]);
    }
}

// ---------------------------------------------------------------------------
__global__ __launch_bounds__(256) void lnorm(
    const float* __restrict__ Hp, const float* __restrict__ gamma,
    const float* __restrict__ beta, float* __restrict__ out) {
  __shared__ float red[8];
  const int rowb = blockIdx.x, tid = threadIdx.x;
  const float* hr = Hp + (size_t)rowb * 1024;
  f32x4 v = *(const f32x4*)&hr[tid * 4];
  float s = v.x + v.y + v.z + v.w;
  float q = v.x * v.x + v.y * v.y + v.z * v.z + v.w * v.w;
#pragma unroll
  for (int d = 1; d < 64; d <<= 1) {
    s += __shfl_xor(s, d, 64);
    q += __shfl_xor(q, d, 64);
  }
  int w = tid >> 6, lane = tid & 63;
  if (lane == 0) { red[w] = s; red[4 + w] = q; }
  __syncthreads();
  s = red[0] + red[1] + red[2] + red[3];
  q = red[4] + red[5] + red[6] + red[7];
  float mu = s * (1.f / 1024.f);
  float var = q * (1.f / 1024.f) - mu * mu;
  float rstd = rsqrtf(var + 1e-12f);
  float* orow = out + (size_t)rowb * 1024;
  f32x4 o;
#pragma unroll
  for (int j = 0; j < 4; j++) {
    int c = tid * 4 + j;
    o[j] = (v[j] - mu) * rstd * gamma[c] + beta[c];
  }
  *(f32x4*)&orow[tid * 4] = o;
}

// ---------------------------------------------------------------------------
extern "C" void kernel_launch(void* const* d_in, const int* in_sizes, int n_in,
                              void* d_out, int out_size, void* d_ws,
                              size_t ws_size, hipStream_t stream) {
  const float* X    = (const float*)d_in[0];
  const float* Wq   = (const float*)d_in[1];
  const float* bq   = (const float*)d_in[2];
  const float* Wk   = (const float*)d_in[3];
  const float* bk   = (const float*)d_in[4];
  const float* Wv   = (const float*)d_in[5];
  const float* bv   = (const float*)d_in[6];
  const float* dist = (const float*)d_in[7];
  const float* Wo   = (const float*)d_in[8];
  const float* bo   = (const float*)d_in[9];
  const float* gam  = (const float*)d_in[10];
  const float* bet  = (const float*)d_in[11];

  const size_t NE = (size_t)8192 * 1024;
  char* ws = (char*)d_ws;
  u16* Qw = (u16*)(ws);
  u16* Kw = (u16*)(ws + 2 * NE);
  u16* Vw = (u16*)(ws + 4 * NE);
  u16* Cw = (u16*)(ws + 6 * NE);
  float* Hp = (float*)ws;  // fp32 pre-LN, overlays dead Q+K

  // d_out (32 MiB fp32) as scratch until lnorm overwrites it.
  char* ob = (char*)d_out;
  u16* Wtq = (u16*)(ob);                // [3072][1024] stacked q,k,v
  u16* Wtk = (u16*)(ob + (2u << 20));
  u16* Wtv = (u16*)(ob + (4u << 20));
  u16* Wto = (u16*)(ob + (6u << 20));
  u16* Xb  = (u16*)(ob + (8u << 20));
  u16* Vtg = (u16*)(ob + (8u << 20));   // overlays Xb (disjoint lifetime)
  u16* distb = (u16*)(ob + (26u << 20));
  float* bias3 = (float*)(ob + (30u << 20));  // stacked q,k,v bias (12 KB)

  dim3 bb(256);
  dim3 gw(16, 16);
  convWt<<<gw, bb, 0, stream>>>(Wq, Wtq);
  convWt<<<gw, bb, 0, stream>>>(Wk, Wtk);
  convWt<<<gw, bb, 0, stream>>>(Wv, Wtv);
  convWt<<<gw, bb, 0, stream>>>(Wo, Wto);
  convX<<<dim3(4096), bb, 0, stream>>>(X, Xb);
  convD<<<dim3(64), bb, 0, stream>>>(dist, distb);
  hipMemcpyAsync(bias3, bq, 4096, hipMemcpyDeviceToDevice, stream);
  hipMemcpyAsync(bias3 + 1024, bk, 4096, hipMemcpyDeviceToDevice, stream);
  hipMemcpyAsync(bias3 + 2048, bv, 4096, hipMemcpyDeviceToDevice, stream);

  // fused QKV GEMM: [8192,1024] @ [3072,1024]^T -> Qw|Kw|Vw segments
  // grid: x = n-row-block (A-panel XCD pinning), y = m-col-block
  gemm_bb<0, 0, 1><<<dim3(64, 24), bb, 0, stream>>>(
      Xb, Wtq, bias3, nullptr, nullptr, Qw, 8192, 1024, 3072, 1.0f);
  transV<<<dim3(16, 128), bb, 0, stream>>>(Vw, Vtg);
  attn<<<dim3(16, 128), bb, 0, stream>>>(Qw, Kw, Vtg, distb, Cw);
  gemm_bb<1, 1, 0><<<dim3(64, 8), bb, 0, stream>>>(
      Cw, Wto, bo, X, Hp, nullptr, 8192, 1024, 1024, 1.0f);
  lnorm<<<dim3(8192), bb, 0, stream>>>(Hp, gam, bet, (float*)d_out);
}

// Round 9
// 406.496 us; speedup vs baseline: 1.3949x; 1.3949x over previous
//
#include <hip/hip_runtime.h>

// ---------------------------------------------------------------------------
// BertAttention (relative_key_query) on MI355X. FP32 I/O, bf16 MFMA compute.
// B=8 S=1024 E=1024 H=16 D=64 M=1024
// R15 (resubmit; previous run died on a container-infra error, not kernel):
//   attn: R11 verbatim (sK[64][72] 16B-aligned rows, XOR8 stride-64 G arrays
//     [measured-best 2.94e7 conflicts; strides 66/70/76 all measured worse,
//     76 catastrophically: 152B rows break b128 alignment], hoisted addrs,
//     u-restricted G, async-STAGE reg prefetch, setprio, deferred rsum,
//     prescaled exp2) + R12 XCD remap (FETCH 142->76MB, time-neutral).
//   GEMM: fused QKV (one launch, stacked Wt), transposed grid (x=row-panel).
//   glue: convWt merged into one z-indexed launch; QKV bias selected
//     in-kernel (no memcpys).
// ---------------------------------------------------------------------------

typedef unsigned short u16;
typedef unsigned int u32;
typedef unsigned long long u64;
typedef __bf16 bf16x8 __attribute__((ext_vector_type(8)));
typedef float  f32x4  __attribute__((ext_vector_type(4)));
typedef int    i32x4  __attribute__((ext_vector_type(4)));

__device__ __forceinline__ float b2f(u16 u) {
  union { u32 i; float f; } x;
  x.i = ((u32)u) << 16;
  return x.f;
}
__device__ __forceinline__ u16 f2b_manual(float f) {
  union { float f; u32 u; } x;
  x.f = f;
  return (u16)((x.u + 0x7FFFu + ((x.u >> 16) & 1u)) >> 16);
}
#if __has_builtin(__builtin_amdgcn_cvt_pk_bf16_f32)
typedef __bf16 bf16x2 __attribute__((ext_vector_type(2)));
__device__ __forceinline__ u32 cvt2(float a, float b) {
  union { bf16x2 v; u32 u; } x;
  x.v = __builtin_amdgcn_cvt_pk_bf16_f32(a, b);
  return x.u;
}
#else
__device__ __forceinline__ u32 cvt2(float a, float b) {
  return (u32)f2b_manual(a) | ((u32)f2b_manual(b) << 16);
}
#endif
__device__ __forceinline__ u16 f2b(float f) { return (u16)(cvt2(f, f) & 0xffffu); }

union LdU { i32x4 i4; bf16x8 b8; };
__device__ __forceinline__ bf16x8 ldb8(const u16* p) {
  LdU u; u.i4 = *(const i32x4*)p; return u.b8;
}
__device__ __forceinline__ void pack8(u16* dst, const float* src) {
  f32x4 lo = *(const f32x4*)src, hi = *(const f32x4*)(src + 4);
  i32x4 v;
  v.x = (int)cvt2(lo.x, lo.y); v.y = (int)cvt2(lo.z, lo.w);
  v.z = (int)cvt2(hi.x, hi.y); v.w = (int)cvt2(hi.z, hi.w);
  *(i32x4*)dst = v;
}
#define MFMA16(a, b, c) __builtin_amdgcn_mfma_f32_16x16x32_bf16((a), (b), (c), 0, 0, 0)

template <int C>
__device__ __forceinline__ float dppmov(float x) {
  union { float f; int i; } a, r;
  a.f = x;
  r.i = __builtin_amdgcn_update_dpp(0, a.i, C, 0xF, 0xF, true);
  return r.f;
}
__device__ __forceinline__ float rsum16(float x) {
  x += dppmov<0xB1>(x);   // quad_perm xor1
  x += dppmov<0x4E>(x);   // quad_perm xor2
  x += dppmov<0x141>(x);  // row_half_mirror (^7)
  x += dppmov<0x140>(x);  // row_mirror (^15)
  return x;
}
__device__ __forceinline__ float fexp2(float x) {
#if __has_builtin(__builtin_amdgcn_exp2f)
  return __builtin_amdgcn_exp2f(x);
#else
  return exp2f(x);
#endif
}

// async global->LDS 16B/lane; LDS dest must be wave-uniform base (HW adds
// lane*16). Fallback: manual copy producing identical layout.
#if __has_builtin(__builtin_amdgcn_global_load_lds)
#define HAS_GLDS 1
typedef __attribute__((address_space(3))) u32 as3_u32;
typedef const __attribute__((address_space(1))) u32 as1_u32;
__device__ __forceinline__ void gld16(const u16* g, u16* lds_wave_base) {
  __builtin_amdgcn_global_load_lds(
      (as1_u32*)g, (as3_u32*)(u32)(u64)lds_wave_base, 16, 0, 0);
}
#else
#define HAS_GLDS 0
__device__ __forceinline__ void gld16_fb(const u16* g, u16* lds_wave_base,
                                         int lane) {
  *(i32x4*)(lds_wave_base + lane * 8) = *(const i32x4*)g;
}
#endif

// sqrt(0.125 * log2(e)) — folded into Q, K, dist at conversion time so the
// softmax exponent needs no per-element scale.
#define SQRT_C2 0.42466090f

// ---------------------------------------------------------------------------
__global__ __launch_bounds__(256) void convX(
    const float* __restrict__ X, u16* __restrict__ Xb) {
  int i = (blockIdx.x * 256 + threadIdx.x) * 8;
  pack8(&Xb[i], &X[i]);
}

__global__ __launch_bounds__(256) void convD(
    const float* __restrict__ dist, u16* __restrict__ distb) {
  int i = (blockIdx.x * 256 + threadIdx.x) * 8;
  if (i < 2047 * 64) {
    float t[8];
#pragma unroll
    for (int j = 0; j < 8; j++) t[j] = dist[i + j] * SQRT_C2;
    pack8(&distb[i], t);
  }
}

// convWt4: 4 weights in one launch (z selects). W[1024][1024] fp32 ->
// Wt[m][k] bf16 (transposed), 64x64 LDS tiles.
__global__ __launch_bounds__(256) void convWt4(
    const float* __restrict__ W0, const float* __restrict__ W1,
    const float* __restrict__ W2, const float* __restrict__ W3,
    u16* __restrict__ Wt) {
  __shared__ float tile[64][65];
  const int tid = threadIdx.x;
  const int k0 = blockIdx.x * 64, m0 = blockIdx.y * 64;
  const int z = blockIdx.z;
  const float* W = (z == 0) ? W0 : (z == 1) ? W1 : (z == 2) ? W2 : W3;
  u16* Wtz = Wt + (size_t)z * 1024 * 1024;
#pragma unroll
  for (int it = 0; it < 4; it++) {
    int row = (tid >> 4) + 16 * it;
    int col = (tid & 15) * 4;
    f32x4 v = *(const f32x4*)&W[(size_t)(k0 + row) * 1024 + m0 + col];
    tile[row][col] = v.x; tile[row][col + 1] = v.y;
    tile[row][col + 2] = v.z; tile[row][col + 3] = v.w;
  }
  __syncthreads();
#pragma unroll
  for (int it = 0; it < 4; it++) {
    int mr = (tid >> 4) + 16 * it;
    int kc = (tid & 15) * 4;
    u32 w0 = cvt2(tile[kc][mr], tile[kc + 1][mr]);
    u32 w1 = cvt2(tile[kc + 2][mr], tile[kc + 3][mr]);
    *(u64*)&Wtz[(size_t)(m0 + mr) * 1024 + k0 + kc] = (u64)w0 | ((u64)w1 << 32);
  }
}

// transV: Vw[b*1024+s][h*64+d] bf16 -> Vt[bh][d][s] bf16.
__global__ __launch_bounds__(256) void transV(
    const u16* __restrict__ V, u16* __restrict__ Vt) {
  __shared__ u16 tile[64][72];
  const int tid = threadIdx.x;
  const int bh = blockIdx.y, b = bh >> 4, h = bh & 15;
  const int s0 = blockIdx.x << 6;
  const u16* Vb = V + (size_t)(b * 1024) * 1024 + h * 64;
  {
    int rp = tid >> 3, a = tid & 7;
    const u16* src = &Vb[(size_t)(s0 + 2 * rp) * 1024 + a * 8];
    i32x4 va = *(const i32x4*)src;
    i32x4 vb2 = *(const i32x4*)(src + 1024);
    u16 ta[8] __attribute__((aligned(16)));
    u16 tb[8] __attribute__((aligned(16)));
    *(i32x4*)ta = va; *(i32x4*)tb = vb2;
    int colb = ((((rp >> 2) ^ a) << 3) | ((2 * rp) & 7));
#pragma unroll
    for (int j = 0; j < 8; j++)
      *(u32*)&tile[a * 8 + j][colb] = (u32)ta[j] | ((u32)tb[j] << 16);
  }
  __syncthreads();
  int d = tid >> 2, cc = tid & 3;
  int sw = (d >> 3) & 7;
  i32x4 lo = *(const i32x4*)&tile[d][((2 * cc) ^ sw) << 3];
  i32x4 hi = *(const i32x4*)&tile[d][((2 * cc + 1) ^ sw) << 3];
  u16* dst = Vt + ((size_t)bh * 64 + d) * 1024 + s0 + cc * 16;
  *(i32x4*)dst = lo;
  *(i32x4*)(dst + 8) = hi;
}

// ---------------------------------------------------------------------------
// GEMM: out[N,M] = A[N,K] @ Wt^T + bias (+ residual). 128x128 tile, BK=64,
// 4 waves x 32x128. Staging via global_load_lds (16B/lane), XOR8 swizzle on
// the GLOBAL address. Grid: x = n-row-block (A-panel XCD pinning via idx%8
// round-robin), y = m-col-block.
// QKV=1: M=3072 stacked weights; per-segment bias pointer + oscale selected
// in-kernel (m0 block-uniform); outputs split into 3 [8192][1024] segments.
// ---------------------------------------------------------------------------
template <int RESID, int OUTF32, int QKV>
__global__ __launch_bounds__(256) void gemm_bb(
    const u16* __restrict__ A, const u16* __restrict__ Wt,
    const float* __restrict__ bias, const float* __restrict__ biasK,
    const float* __restrict__ biasV, const float* __restrict__ resid,
    float* __restrict__ outF, u16* __restrict__ outB, int N, int K, int M) {
  __shared__ u16 sA[128 * 64];
  __shared__ u16 sW[128 * 64];

  const int tid = threadIdx.x;
  const int lane = tid & 63, w = tid >> 6;
  const int quad = lane >> 4, lb = lane & 15;
  const int m0 = blockIdx.y * 128, n0 = blockIdx.x * 128;

  const int srow = lane >> 3;
  const int gcol = ((lane & 7) ^ srow) << 3;  // XOR8 swizzle on global side

  f32x4 acc[2][8] = {};

  for (int k0 = 0; k0 < K; k0 += 64) {
#pragma unroll
    for (int j = 0; j < 4; j++) {
      int rb = (4 * w + j) * 8;
      const u16* ga = &A[(size_t)(n0 + rb + srow) * K + k0 + gcol];
      const u16* gw = &Wt[(size_t)(m0 + rb + srow) * K + k0 + gcol];
#if HAS_GLDS
      gld16(ga, &sA[rb * 64]);
      gld16(gw, &sW[rb * 64]);
#else
      gld16_fb(ga, &sA[rb * 64], lane);
      gld16_fb(gw, &sW[rb * 64], lane);
#endif
    }
    __syncthreads();

    const int r0 = 32 * w + lb;
    const int sw0 = r0 & 7;  // (r0+16)&7 == sw0
    bf16x8 a00 = ldb8(&sA[r0 * 64 + ((quad ^ sw0) << 3)]);
    bf16x8 a01 = ldb8(&sA[r0 * 64 + (((4 + quad) ^ sw0) << 3)]);
    bf16x8 a10 = ldb8(&sA[(r0 + 16) * 64 + ((quad ^ sw0) << 3)]);
    bf16x8 a11 = ldb8(&sA[(r0 + 16) * 64 + (((4 + quad) ^ sw0) << 3)]);
#pragma unroll
    for (int t = 0; t < 8; t++) {
      int n = 16 * t + lb;
      int swn = n & 7;
      bf16x8 b0 = ldb8(&sW[n * 64 + ((quad ^ swn) << 3)]);
      bf16x8 b1 = ldb8(&sW[n * 64 + (((4 + quad) ^ swn) << 3)]);
      acc[0][t] = MFMA16(a00, b0, acc[0][t]);
      acc[0][t] = MFMA16(a01, b1, acc[0][t]);
      acc[1][t] = MFMA16(a10, b0, acc[1][t]);
      acc[1][t] = MFMA16(a11, b1, acc[1][t]);
    }
    __syncthreads();
  }

  const float* bp = bias;
  u16* outSeg = outB;
  float osc = 1.0f;
  int mbase = m0;
  if (QKV) {
    int seg = m0 >> 10;
    bp = (seg == 0) ? bias : (seg == 1) ? biasK : biasV;
    outSeg = outB + (size_t)seg * ((size_t)8192 * 1024);
    osc = (seg < 2) ? SQRT_C2 : 1.0f;
    mbase = m0 & 1023;
  }

#pragma unroll
  for (int half = 0; half < 2; half++)
#pragma unroll
    for (int t = 0; t < 8; t++) {
      int colw = mbase + 16 * t + lb;   // col within segment
      float bv = bp[colw];
#pragma unroll
      for (int i = 0; i < 4; i++) {
        int rowg = n0 + 32 * w + 16 * half + quad * 4 + i;
        float v = acc[half][t][i] + bv;
        if (RESID) v += resid[(size_t)rowg * M + colw];
        if (QKV) v *= osc;
        if (OUTF32) outF[(size_t)rowg * M + colw] = v;
        else        outSeg[(size_t)rowg * (QKV ? 1024 : M) + colw] = f2b(v);
      }
    }
}

// ---------------------------------------------------------------------------
// Fused attention: one block = (b, h, 64 q-rows), 16 k-tiles of 64.
// R11 schedule + layouts VERBATIM (register prefetch before QK^T, ds_write
// in the C->A gap, setprio, hoisted addrs, u-restricted G, deferred rsum,
// prescaled exp2, stride-64 XOR8 G arrays, sK[64][72] 16B-aligned rows)
// + R12 XCD remap only.
// ---------------------------------------------------------------------------
__global__ __launch_bounds__(256) void attn(
    const u16* __restrict__ Q, const u16* __restrict__ Kv,
    const u16* __restrict__ Vt, const u16* __restrict__ distb,
    u16* __restrict__ ctx) {
  __shared__ u16 sQ[64][72];
  __shared__ u16 sK[64][72];      // probs overlay after barrier B
  __shared__ u16 sVt[64][72];     // V^T [d][r]
  __shared__ u16 sP[128][72];     // dist window, circular
  __shared__ u16 sGq[128 * 64];   // Gq[c][rl], XOR8-swizzled cols
  __shared__ u16 sGk[128 * 64];   // Gk[c][cl], XOR8-swizzled cols

  const int tid = threadIdx.x;
  const int lane = tid & 63, w = tid >> 6;
  const int quad = lane >> 4, lb = lane & 15;
  // XCD-aware remap (bijective on 16x128 grid)
  const int f = blockIdx.y * 16 + blockIdx.x;
  const int xcd = f & 7, slot = f >> 3;
  const int bh = (xcd << 4) | (slot & 15);
  const int q0 = (slot >> 4) << 6;
  const int b = bh >> 4, h = bh & 15;
  const int S = 1024, E = 1024;
  const u16* Qb = Q  + (size_t)(b * S) * E + h * 64;
  const u16* Kb = Kv + (size_t)(b * S) * E + h * 64;
  const u16* Vtb = Vt + (size_t)bh * 64 * 1024;

  const int sr = tid >> 3, sc8 = (tid & 7) << 3;

  // pre-loop staging: Q, K/V tile 0, full 128-row dist window
  {
    *(i32x4*)&sQ[sr][sc8] = *(const i32x4*)&Qb[(size_t)(q0 + sr) * E + sc8];
    *(i32x4*)&sQ[sr + 32][sc8] =
        *(const i32x4*)&Qb[(size_t)(q0 + sr + 32) * E + sc8];
    *(i32x4*)&sK[sr][sc8] = *(const i32x4*)&Kb[(size_t)sr * E + sc8];
    *(i32x4*)&sK[sr + 32][sc8] =
        *(const i32x4*)&Kb[(size_t)(sr + 32) * E + sc8];
    *(i32x4*)&sVt[sr][sc8] = *(const i32x4*)&Vtb[(size_t)sr * 1024 + sc8];
    *(i32x4*)&sVt[sr + 32][sc8] =
        *(const i32x4*)&Vtb[(size_t)(sr + 32) * 1024 + sc8];
    const int dbase = q0 + 960;
#pragma unroll
    for (int j = 0; j < 4; j++) {
      int p = sr + 32 * j;
      int g = dbase + p;
      if (g > 2046) g = 2046;
      *(i32x4*)&sP[p][sc8] = *(const i32x4*)&distb[(size_t)g * 64 + sc8];
    }
  }
  __syncthreads();  // barrier A (tile 0)

  const int row = 16 * w + lb;
  bf16x8 aq0 = ldb8(&sQ[row][quad * 8]);
  bf16x8 aq1 = ldb8(&sQ[row][32 + quad * 8]);

  // ---- hoisted kt-invariant addresses (u16-element units) ----
  const u16* kb  = &sK[lb][quad * 8];        // QK B: +1152*t, +32
  const u16* vbp = &sVt[lb][quad * 8];       // PV B: +1152*t, +32
  const u16* akb = &sK[row][quad * 8];       // K/P A-frags: +0, +32
  const u16* pb  = &sP[lb][quad * 8];        // dist B: row 16u+lb -> +1152*u
  u16* gqsb = &sGq[lb * 64 + ((16 * w + 4 * quad) ^ ((lb & 7) << 3))];
  u16* gksb = &sGk[lb * 64 + ((16 * w + 4 * quad) ^ ((lb & 7) << 3))];
  u16* psb  = &sK[16 * w + 4 * quad][lb];    // probs store: +72*i+16*t
  const int rl_ = 16 * w + 4 * quad;
  const u16* gqa_[4];
  const u16* gka_[4][4];
#pragma unroll
  for (int i = 0; i < 4; i++) {
    int rl = rl_ + i;
    int c3 = rl - lb + 15;                   // c at t=3 (in [0,78])
    int sw8 = (c3 & 7) << 3;                 // t-invariant (16 | 8)
    gqa_[i] = &sGq[(c3 << 6) + (rl ^ sw8)];  // gather: +1024*(3-t)
#pragma unroll
    for (int t = 0; t < 4; t++) {
      int c = rl - (16 * t + lb) + 63;
      gka_[i][t] = &sGk[(c << 6) + ((16 * t + lb) ^ sw8)];
    }
  }
  // staging running pointers (advance per tile)
  const u16* kg0 = Kb + (size_t)(64 + sr) * E + sc8;
  const u16* kg1 = kg0 + (size_t)32 * E;
  const u16* vg0 = Vtb + (size_t)sr * 1024 + 64 + sc8;
  const u16* vg1 = vg0 + (size_t)32 * 1024;
  const u16* dg0 = distb + (size_t)(q0 - 64 + 960 + sr) * 64 + sc8;
  const u16* dg1 = dg0 + (size_t)32 * 64;
  u16* wk0 = &sK[sr][sc8];  u16* wk1 = &sK[sr + 32][sc8];
  u16* wv0 = &sVt[sr][sc8]; u16* wv1 = &sVt[sr + 32][sc8];
  u16* wp0 = &sP[sr][sc8];  u16* wp1 = &sP[sr + 32][sc8];

  const int uqlo = w, uqhi = w + 4;      // Gq active u-range (5 blocks)
  const int uklo = 3 - w, ukhi = 7 - w;  // Gk active u-range (5 blocks)

  f32x4 accO[4] = {};
  float l_i[4] = {0.f, 0.f, 0.f, 0.f};

  for (int kt = 0; kt < 16; kt++) {
    const int xorv = (kt & 1) << 6;

    // --- register prefetch of tile kt+1 ---
    i32x4 kr0, kr1, vr0, vr1, dr0, dr1;
    if (kt < 15) {
      kr0 = *(const i32x4*)kg0;
      kr1 = *(const i32x4*)kg1;
      vr0 = *(const i32x4*)vg0;
      vr1 = *(const i32x4*)vg1;
      dr0 = *(const i32x4*)dg0;
      dr1 = *(const i32x4*)dg1;
    }

    // --- QK^T ---
    __builtin_amdgcn_s_setprio(1);
    f32x4 accS[4] = {};
#pragma unroll
    for (int t = 0; t < 4; t++) {
      bf16x8 b0 = ldb8(kb + 1152 * t);
      bf16x8 b1 = ldb8(kb + 1152 * t + 32);
      accS[t] = MFMA16(aq0, b0, accS[t]);
      accS[t] = MFMA16(aq1, b1, accS[t]);
    }
    // --- rel-bias GEMMs (u-restricted; imm-folded store offsets) ---
    bf16x8 ak0 = ldb8(akb);
    bf16x8 ak1 = ldb8(akb + 32);
    const u16* pbA = pb + (xorv ? 4608 : 0);    // u<4 rows
    const u16* pbB = pb + (xorv ? -4608 : 0);   // u>=4 rows
#pragma unroll
    for (int u = 0; u < 8; u++) {
      const bool doq = (u >= uqlo) && (u <= uqhi);
      const bool dok = (u >= uklo) && (u <= ukhi);
      if (doq || dok) {
        const u16* pp = (u < 4 ? pbA : pbB) + 1152 * u;
        bf16x8 p0 = ldb8(pp);
        bf16x8 p1 = ldb8(pp + 32);
        if (doq) {
          f32x4 gq = {};
          gq = MFMA16(aq0, p0, gq);
          gq = MFMA16(aq1, p1, gq);
          *(u32*)(gqsb + 1024 * u) = cvt2(gq[0], gq[1]);
          *(u32*)(gqsb + 1024 * u + 2) = cvt2(gq[2], gq[3]);
        }
        if (dok) {
          f32x4 gk = {};
          gk = MFMA16(ak0, p0, gk);
          gk = MFMA16(ak1, p1, gk);
          *(u32*)(gksb + 1024 * u) = cvt2(gk[0], gk[1]);
          *(u32*)(gksb + 1024 * u + 2) = cvt2(gk[2], gk[3]);
        }
      }
    }
    __builtin_amdgcn_s_setprio(0);
    __syncthreads();  // barrier B (G read cross-wave; sK dead after this)

    // --- bias gather + fixed-max softmax (exp2 domain, prescaled) ---
    float pr[4][4];
#pragma unroll
    for (int t = 0; t < 4; t++) {
#pragma unroll
      for (int i = 0; i < 4; i++) {
        float s = accS[t][i] + b2f(gqa_[i][1024 * (3 - t)]) +
                  b2f(*gka_[i][t]);
        float e = fexp2(s);
        pr[t][i] = e;
        l_i[i] += e;
      }
    }

    // probs -> sK overlay (own-wave rows only; imm-folded offsets)
#pragma unroll
    for (int t = 0; t < 4; t++)
#pragma unroll
      for (int i = 0; i < 4; i++)
        psb[72 * i + 16 * t] = f2b(pr[t][i]);

    // --- PV ---
    bf16x8 ap0 = ldb8(akb);
    bf16x8 ap1 = ldb8(akb + 32);
    __builtin_amdgcn_s_setprio(1);
#pragma unroll
    for (int t = 0; t < 4; t++) {
      bf16x8 v0 = ldb8(vbp + 1152 * t);
      bf16x8 v1 = ldb8(vbp + 1152 * t + 32);
      accO[t] = MFMA16(ap0, v0, accO[t]);
      accO[t] = MFMA16(ap1, v1, accO[t]);
    }
    __builtin_amdgcn_s_setprio(0);
    __syncthreads();  // barrier C (PV reads of sK/sVt done block-wide)

    // --- write prefetched tile kt+1 to LDS; barrier A for next tile ---
    if (kt < 15) {
      const int pxn = ((kt + 1) & 1) ? 4608 : 0;
      *(i32x4*)wk0 = kr0;
      *(i32x4*)wk1 = kr1;
      *(i32x4*)wv0 = vr0;
      *(i32x4*)wv1 = vr1;
      *(i32x4*)(wp0 + pxn) = dr0;
      *(i32x4*)(wp1 + pxn) = dr1;
      kg0 += (size_t)64 * E; kg1 += (size_t)64 * E;
      vg0 += 64;             vg1 += 64;
      dg0 -= 64 * 64;        dg1 -= 64 * 64;
      __syncthreads();  // barrier A (tile kt+1)
    }
  }

#pragma unroll
  for (int i = 0; i < 4; i++) l_i[i] = rsum16(l_i[i]);

  u16* Cb = ctx + (size_t)(b * S) * E + h * 64;
#pragma unroll
  for (int t = 0; t < 4; t++)
#pragma unroll
    for (int i = 0; i < 4; i++) {
      int rl = 16 * w + quad * 4 + i;
      Cb[(size_t)(q0 + rl) * E + 16 * t + lb] = f2b(accO[t][i] / l_i[i]);
    }
}

// ---------------------------------------------------------------------------
__global__ __launch_bounds__(256) void lnorm(
    const float* __restrict__ Hp, const float* __restrict__ gamma,
    const float* __restrict__ beta, float* __restrict__ out) {
  __shared__ float red[8];
  const int rowb = blockIdx.x, tid = threadIdx.x;
  const float* hr = Hp + (size_t)rowb * 1024;
  f32x4 v = *(const f32x4*)&hr[tid * 4];
  float s = v.x + v.y + v.z + v.w;
  float q = v.x * v.x + v.y * v.y + v.z * v.z + v.w * v.w;
#pragma unroll
  for (int d = 1; d < 64; d <<= 1) {
    s += __shfl_xor(s, d, 64);
    q += __shfl_xor(q, d, 64);
  }
  int w = tid >> 6, lane = tid & 63;
  if (lane == 0) { red[w] = s; red[4 + w] = q; }
  __syncthreads();
  s = red[0] + red[1] + red[2] + red[3];
  q = red[4] + red[5] + red[6] + red[7];
  float mu = s * (1.f / 1024.f);
  float var = q * (1.f / 1024.f) - mu * mu;
  float rstd = rsqrtf(var + 1e-12f);
  float* orow = out + (size_t)rowb * 1024;
  f32x4 o;
#pragma unroll
  for (int j = 0; j < 4; j++) {
    int c = tid * 4 + j;
    o[j] = (v[j] - mu) * rstd * gamma[c] + beta[c];
  }
  *(f32x4*)&orow[tid * 4] = o;
}

// ---------------------------------------------------------------------------
extern "C" void kernel_launch(void* const* d_in, const int* in_sizes, int n_in,
                              void* d_out, int out_size, void* d_ws,
                              size_t ws_size, hipStream_t stream) {
  const float* X    = (const float*)d_in[0];
  const float* Wq   = (const float*)d_in[1];
  const float* bq   = (const float*)d_in[2];
  const float* Wk   = (const float*)d_in[3];
  const float* bk   = (const float*)d_in[4];
  const float* Wv   = (const float*)d_in[5];
  const float* bv   = (const float*)d_in[6];
  const float* dist = (const float*)d_in[7];
  const float* Wo   = (const float*)d_in[8];
  const float* bo   = (const float*)d_in[9];
  const float* gam  = (const float*)d_in[10];
  const float* bet  = (const float*)d_in[11];

  const size_t NE = (size_t)8192 * 1024;
  char* ws = (char*)d_ws;
  u16* Qw = (u16*)(ws);
  u16* Kw = (u16*)(ws + 2 * NE);
  u16* Vw = (u16*)(ws + 4 * NE);
  u16* Cw = (u16*)(ws + 6 * NE);
  float* Hp = (float*)ws;  // fp32 pre-LN, overlays dead Q+K

  // d_out (32 MiB fp32) as scratch until lnorm overwrites it.
  char* ob = (char*)d_out;
  u16* Wt4 = (u16*)(ob);                // [4096][1024]: q,k,v,o stacked
  u16* Wto = (u16*)(ob + (6u << 20));   // = Wt4 + 3*1024*1024
  u16* Xb  = (u16*)(ob + (8u << 20));
  u16* Vtg = (u16*)(ob + (8u << 20));   // overlays Xb (disjoint lifetime)
  u16* distb = (u16*)(ob + (26u << 20));

  dim3 bb(256);
  convWt4<<<dim3(16, 16, 4), bb, 0, stream>>>(Wq, Wk, Wv, Wo, Wt4);
  convX<<<dim3(4096), bb, 0, stream>>>(X, Xb);
  convD<<<dim3(64), bb, 0, stream>>>(dist, distb);

  // fused QKV GEMM: [8192,1024] @ [3072,1024]^T -> Qw|Kw|Vw segments
  // grid: x = n-row-block (A-panel XCD pinning), y = m-col-block
  gemm_bb<0, 0, 1><<<dim3(64, 24), bb, 0, stream>>>(
      Xb, Wt4, bq, bk, bv, nullptr, nullptr, Qw, 8192, 1024, 3072);
  transV<<<dim3(16, 128), bb, 0, stream>>>(Vw, Vtg);
  attn<<<dim3(16, 128), bb, 0, stream>>>(Qw, Kw, Vtg, distb, Cw);
  gemm_bb<1, 1, 0><<<dim3(64, 8), bb, 0, stream>>>(
      Cw, Wto, bo, nullptr, nullptr, X, Hp, nullptr, 8192, 1024, 1024);
  lnorm<<<dim3(8192), bb, 0, stream>>>(Hp, gam, bet, (float*)d_out);
}